// Round 1
// baseline (913.906 us; speedup 1.0000x reference)
//
#include <hip/hip_runtime.h>
#include <math.h>

#define Bq 64
#define Tq 1024
#define Nq 128

// ---------------------------------------------------------------------------
// Kernel 1: forward algorithm (log-partition) — one block per batch chain.
// Thread n owns state n. E-column exp(trans[:,n]) lives in 128 VGPRs.
// Per step: p[m] = exp(alpha[m]-mx) broadcast via LDS; s[n] = sum_m p[m]*E[m][n]
// (plain FMA); alpha[n] = mx + log(s) + emit[t][n].
// ---------------------------------------------------------------------------
__global__ __launch_bounds__(128, 1)
void crf_forward_kernel(const float* __restrict__ emissions,
                        const int* __restrict__ token_sizes,
                        const float* __restrict__ transitions,
                        const float* __restrict__ head,
                        const float* __restrict__ last,
                        float* __restrict__ out) {
    const int b = blockIdx.x;
    const int n = threadIdx.x;      // state index 0..127
    const int lane = n & 63;
    const int wid = n >> 6;         // wave id 0..1

    __shared__ float p_lds[Nq];
    __shared__ float redmax[2];
    __shared__ float redsum[2];

    // Load E column n into registers: e[m] = exp(trans[m][n]).
    // For fixed m the lanes read consecutive addresses -> coalesced.
    float e[Nq];
    #pragma unroll
    for (int m = 0; m < Nq; ++m) {
        e[m] = __expf(transitions[m * Nq + n]);
    }

    const float* em = emissions + (size_t)b * Tq * Nq;
    const int tsz = token_sizes[b];   // in [T/2, T], uniform per block

    // alpha0 = head + emissions[:,0]
    float a = head[n] + em[n];

    for (int t = 1; t < tsz; ++t) {
        // issue emission load early to hide latency under the reduction
        float emit = em[t * Nq + n];

        // global max of alpha across 128 threads
        float w = a;
        #pragma unroll
        for (int off = 32; off >= 1; off >>= 1)
            w = fmaxf(w, __shfl_xor(w, off, 64));
        if (lane == 0) redmax[wid] = w;
        __syncthreads();
        float mx = fmaxf(redmax[0], redmax[1]);

        // broadcast p[m] = exp(alpha[m] - mx)
        p_lds[n] = __expf(a - mx);
        __syncthreads();

        // s = sum_m p[m] * E[m][n]   (float4 broadcast reads, register FMAs)
        float s = 0.f;
        const float4* p4 = (const float4*)p_lds;
        #pragma unroll
        for (int mg = 0; mg < Nq / 4; ++mg) {
            float4 pv = p4[mg];
            s = fmaf(pv.x, e[4 * mg + 0], s);
            s = fmaf(pv.y, e[4 * mg + 1], s);
            s = fmaf(pv.z, e[4 * mg + 2], s);
            s = fmaf(pv.w, e[4 * mg + 3], s);
        }
        a = mx + __logf(s) + emit;
        // WAR safety: next iteration's writes to p_lds/redmax are separated
        // from this iteration's reads by at least one __syncthreads().
    }

    // log_partitions[b] = lse_n(alpha[n] + last[n])
    float v = a + last[n];
    float w = v;
    #pragma unroll
    for (int off = 32; off >= 1; off >>= 1)
        w = fmaxf(w, __shfl_xor(w, off, 64));
    if (lane == 0) redmax[wid] = w;
    __syncthreads();
    float mx = fmaxf(redmax[0], redmax[1]);
    float pe = __expf(v - mx);
    float sum = pe;
    #pragma unroll
    for (int off = 32; off >= 1; off >>= 1)
        sum += __shfl_xor(sum, off, 64);
    if (lane == 0) redsum[wid] = sum;
    __syncthreads();
    if (n == 0) {
        out[b] = mx + __logf(redsum[0] + redsum[1]);
    }
}

// ---------------------------------------------------------------------------
// Kernel 2: gold-path score — masked gather-sum per batch.
// log_scores[b] = sum_t<tsz emit[t, tg[t]] + sum_{1<=t<tsz} trans[tg[t-1],tg[t]]
//                 + head[tg[0]] + last[tg[tsz-1]]
// ---------------------------------------------------------------------------
__global__ __launch_bounds__(256)
void crf_score_kernel(const float* __restrict__ emissions,
                      const int* __restrict__ token_sizes,
                      const int* __restrict__ targets,
                      const float* __restrict__ transitions,
                      const float* __restrict__ head,
                      const float* __restrict__ last,
                      float* __restrict__ out) {
    const int b = blockIdx.x;
    const int tid = threadIdx.x;
    const int tsz = token_sizes[b];
    const int* tg = targets + b * Tq;
    const float* em = emissions + (size_t)b * Tq * Nq;

    float local = 0.f;
    for (int t = tid; t < tsz; t += 256) {
        int cur = tg[t];
        local += em[t * Nq + cur];
        if (t >= 1) local += transitions[tg[t - 1] * Nq + cur];
    }
    #pragma unroll
    for (int off = 32; off >= 1; off >>= 1)
        local += __shfl_xor(local, off, 64);

    __shared__ float wsum[4];
    if ((tid & 63) == 0) wsum[tid >> 6] = local;
    __syncthreads();
    if (tid == 0) {
        float tot = wsum[0] + wsum[1] + wsum[2] + wsum[3];
        tot += head[tg[0]] + last[tg[tsz - 1]];
        out[Bq + b] = tot;
    }
}

extern "C" void kernel_launch(void* const* d_in, const int* in_sizes, int n_in,
                              void* d_out, int out_size, void* d_ws, size_t ws_size,
                              hipStream_t stream) {
    const float* emissions   = (const float*)d_in[0];
    const int*   token_sizes = (const int*)d_in[1];
    const int*   targets     = (const int*)d_in[2];
    const float* transitions = (const float*)d_in[3];  // (1,1,128,128)
    const float* head        = (const float*)d_in[4];  // (1,1,128)
    const float* last        = (const float*)d_in[5];  // (1,1,128)
    float* out = (float*)d_out;                        // (2,64,1) flat

    crf_forward_kernel<<<Bq, 128, 0, stream>>>(emissions, token_sizes,
                                               transitions, head, last, out);
    crf_score_kernel<<<Bq, 256, 0, stream>>>(emissions, token_sizes, targets,
                                             transitions, head, last, out);
}